// Round 1
// baseline (1701.819 us; speedup 1.0000x reference)
//
#include <hip/hip_runtime.h>
#include <hip/hip_bf16.h>
#include <math.h>

// Problem constants (from reference)
#define IN_F 128
#define HID 64
#define HEADS 4
#define HD0 (HEADS * HID)   // 256
#define OUT_F 64
// NOISE_SCALE = sqrt(2*log(1.25/0.05))
#define NOISE_SCALE 2.5372725354060904f

// ---------- helpers: order-preserving float<->uint for atomicMax ----------
__device__ __forceinline__ unsigned f2ord(float f) {
    unsigned u = __float_as_uint(f);
    return (u & 0x80000000u) ? ~u : (u | 0x80000000u);
}
__device__ __forceinline__ float ord2f(unsigned u) {
    u = (u & 0x80000000u) ? (u & 0x7fffffffu) : ~u;
    return __uint_as_float(u);
}

// ---------- GEMM: C[M,Nc] = A[M,K] @ B[K,Nc], row-major, fp32 ----------
#define BM 64
#define BN 64
#define BKT 16
#define TM 4
#define TN 4
__global__ __launch_bounds__(256) void gemm_kernel(
    const float* __restrict__ A, const float* __restrict__ B,
    float* __restrict__ C, int M, int K, int Nc) {
    __shared__ float As[BKT][BM + 1];
    __shared__ float Bs[BKT][BN + 1];
    int tid = threadIdx.x;
    int tx = tid % 16, ty = tid / 16;
    int row0 = blockIdx.y * BM;
    int col0 = blockIdx.x * BN;
    float acc[TM][TN] = {};
    for (int k0 = 0; k0 < K; k0 += BKT) {
        // load A tile (BM x BKT)
        for (int i = tid; i < BM * BKT; i += 256) {
            int m = i / BKT, kk = i % BKT;
            int gm = row0 + m;
            As[kk][m] = (gm < M) ? A[(size_t)gm * K + (k0 + kk)] : 0.f;
        }
        // load B tile (BKT x BN)
        for (int i = tid; i < BKT * BN; i += 256) {
            int kk = i / BN, n = i % BN;
            Bs[kk][n] = B[(size_t)(k0 + kk) * Nc + col0 + n];
        }
        __syncthreads();
#pragma unroll
        for (int kk = 0; kk < BKT; ++kk) {
            float a[TM], b[TN];
#pragma unroll
            for (int i = 0; i < TM; i++) a[i] = As[kk][ty * TM + i];
#pragma unroll
            for (int j = 0; j < TN; j++) b[j] = Bs[kk][tx * TN + j];
#pragma unroll
            for (int i = 0; i < TM; i++)
#pragma unroll
                for (int j = 0; j < TN; j++) acc[i][j] += a[i] * b[j];
        }
        __syncthreads();
    }
#pragma unroll
    for (int i = 0; i < TM; i++) {
        int gm = row0 + ty * TM + i;
        if (gm >= M) continue;
#pragma unroll
        for (int j = 0; j < TN; j++) {
            C[(size_t)gm * Nc + col0 + tx * TN + j] = acc[i][j];
        }
    }
}

// ---------- el/er: per (node, head) dot(h[n,h,:], al/ar[h,:]) over D=64 ----------
template <int H>
__global__ __launch_bounds__(256) void eler_kernel(
    const float* __restrict__ h, const float* __restrict__ al,
    const float* __restrict__ ar, float* __restrict__ el,
    float* __restrict__ er, int N) {
    int gt = blockIdx.x * blockDim.x + threadIdx.x;
    int wave = gt >> 6;
    int lane = gt & 63;
    int n = wave / H, hd = wave % H;
    if (n >= N) return;
    float v = h[(size_t)n * (H * 64) + hd * 64 + lane];
    float a = v * al[hd * 64 + lane];
    float b = v * ar[hd * 64 + lane];
#pragma unroll
    for (int off = 32; off > 0; off >>= 1) {
        a += __shfl_down(a, off);
        b += __shfl_down(b, off);
    }
    if (lane == 0) {
        el[n * H + hd] = a;
        er[n * H + hd] = b;
    }
}

// ---------- edge scores + segment max ----------
template <int H>
__global__ __launch_bounds__(256) void edge_score_kernel(
    const int* __restrict__ src, const int* __restrict__ dst,
    const float* __restrict__ el, const float* __restrict__ er,
    float* __restrict__ sc, unsigned* __restrict__ emax, int E) {
    int i = blockIdx.x * blockDim.x + threadIdx.x;
    if (i >= E * H) return;
    int ed = i / H, hd = i % H;
    int s = src[ed], d = dst[ed];
    float v = el[s * H + hd] + er[d * H + hd];
    v = v > 0.f ? v : 0.2f * v;  // leaky_relu slope 0.2
    sc[i] = v;
    atomicMax(&emax[d * H + hd], f2ord(v));
}

// ---------- exp(e - max) + segment sum ----------
template <int H>
__global__ __launch_bounds__(256) void edge_exp_kernel(
    const int* __restrict__ dst, float* __restrict__ sc,
    const unsigned* __restrict__ emax, float* __restrict__ denom, int E) {
    int i = blockIdx.x * blockDim.x + threadIdx.x;
    if (i >= E * H) return;
    int ed = i / H, hd = i % H;
    int d = dst[ed];
    float m = ord2f(emax[d * H + hd]);
    float a = expf(sc[i] - m);
    sc[i] = a;
    atomicAdd(&denom[d * H + hd], a);
}

// ---------- scatter aggregation: out[dst] += alpha * h[src] ----------
template <int H>
__global__ __launch_bounds__(256) void edge_agg_kernel(
    const int* __restrict__ src, const int* __restrict__ dst,
    const float* __restrict__ h, const float* __restrict__ alpha,
    const float* __restrict__ denom, float* __restrict__ out, int E) {
    const int HD = H * 64;
    size_t gi = (size_t)blockIdx.x * blockDim.x + threadIdx.x;
    if (gi >= (size_t)E * HD) return;
    int ed = (int)(gi / HD);
    int r = (int)(gi % HD);
    int hd = r >> 6;
    int s = src[ed], d = dst[ed];
    float a = alpha[(size_t)ed * H + hd] / denom[d * H + hd];
    float v = h[(size_t)s * HD + r] * a;
    atomicAdd(&out[(size_t)d * HD + r], v);
}

// ---------- layer-0 epilogue: bias + leaky_relu(0.01) + noise ----------
__global__ __launch_bounds__(256) void post0_kernel(
    float* __restrict__ agg, const float* __restrict__ b,
    const float* __restrict__ noise, size_t total) {
    size_t i = (size_t)blockIdx.x * blockDim.x + threadIdx.x;
    if (i >= total) return;
    float v = agg[i] + b[i % HD0];
    v = v > 0.f ? v : 0.01f * v;
    agg[i] = v + NOISE_SCALE * noise[i];
}

// ---------- layer-1 epilogue: bias only ----------
__global__ __launch_bounds__(256) void post1_kernel(
    float* __restrict__ out, const float* __restrict__ b, size_t total) {
    size_t i = (size_t)blockIdx.x * blockDim.x + threadIdx.x;
    if (i >= total) return;
    out[i] += b[i & 63];
}

extern "C" void kernel_launch(void* const* d_in, const int* in_sizes, int n_in,
                              void* d_out, int out_size, void* d_ws, size_t ws_size,
                              hipStream_t stream) {
    const float* x     = (const float*)d_in[0];
    const int*   src   = (const int*)d_in[1];
    const int*   dst   = (const int*)d_in[2];
    const float* W0    = (const float*)d_in[3];
    const float* al0   = (const float*)d_in[4];
    const float* ar0   = (const float*)d_in[5];
    const float* b0    = (const float*)d_in[6];
    const float* W1    = (const float*)d_in[7];
    const float* al1   = (const float*)d_in[8];
    const float* ar1   = (const float*)d_in[9];
    const float* b1    = (const float*)d_in[10];
    const float* noise = (const float*)d_in[11];

    const int N = in_sizes[0] / IN_F;   // 100000
    const int E = in_sizes[1];          // 900000

    // Workspace layout (floats)
    float* ws = (float*)d_ws;
    float* h0    = ws;                          // N*256 (reused as h1: N*64)
    float* agg0  = h0 + (size_t)N * HD0;        // N*256
    float* sc    = agg0 + (size_t)N * HD0;      // E*4 (layer1 reuses first E)
    float* el    = sc + (size_t)E * HEADS;      // N*4
    float* er    = el + (size_t)N * HEADS;      // N*4
    unsigned* emax = (unsigned*)(er + (size_t)N * HEADS);  // N*4
    float* denom = (float*)emax + (size_t)N * HEADS;        // N*4
    float* h1    = h0;  // alias: h0 dead after layer-0 aggregation

    // ===================== Layer 0 =====================
    {
        dim3 grid(HD0 / BN, (N + BM - 1) / BM);
        gemm_kernel<<<grid, 256, 0, stream>>>(x, W0, h0, N, IN_F, HD0);
    }
    {
        int waves = N * HEADS;
        int blocks = (waves * 64 + 255) / 256;
        eler_kernel<HEADS><<<blocks, 256, 0, stream>>>(h0, al0, ar0, el, er, N);
    }
    hipMemsetAsync(emax, 0, (size_t)N * HEADS * sizeof(unsigned), stream);
    hipMemsetAsync(denom, 0, (size_t)N * HEADS * sizeof(float), stream);
    hipMemsetAsync(agg0, 0, (size_t)N * HD0 * sizeof(float), stream);
    {
        int total = E * HEADS;
        edge_score_kernel<HEADS><<<(total + 255) / 256, 256, 0, stream>>>(
            src, dst, el, er, sc, emax, E);
        edge_exp_kernel<HEADS><<<(total + 255) / 256, 256, 0, stream>>>(
            dst, sc, emax, denom, E);
    }
    {
        size_t total = (size_t)E * HD0;
        edge_agg_kernel<HEADS><<<(unsigned)((total + 255) / 256), 256, 0, stream>>>(
            src, dst, h0, sc, denom, agg0, E);
    }
    {
        size_t total = (size_t)N * HD0;
        post0_kernel<<<(unsigned)((total + 255) / 256), 256, 0, stream>>>(
            agg0, b0, noise, total);
    }

    // ===================== Layer 1 =====================
    {
        dim3 grid(OUT_F / BN, (N + BM - 1) / BM);
        gemm_kernel<<<grid, 256, 0, stream>>>(agg0, W1, h1, N, HD0, OUT_F);
    }
    {
        int waves = N;  // H=1
        int blocks = (waves * 64 + 255) / 256;
        eler_kernel<1><<<blocks, 256, 0, stream>>>(h1, al1, ar1, el, er, N);
    }
    hipMemsetAsync(emax, 0, (size_t)N * sizeof(unsigned), stream);
    hipMemsetAsync(denom, 0, (size_t)N * sizeof(float), stream);
    hipMemsetAsync(d_out, 0, (size_t)N * OUT_F * sizeof(float), stream);
    {
        int total = E;
        edge_score_kernel<1><<<(total + 255) / 256, 256, 0, stream>>>(
            src, dst, el, er, sc, emax, E);
        edge_exp_kernel<1><<<(total + 255) / 256, 256, 0, stream>>>(
            dst, sc, emax, denom, E);
    }
    {
        size_t total = (size_t)E * OUT_F;
        edge_agg_kernel<1><<<(unsigned)((total + 255) / 256), 256, 0, stream>>>(
            src, dst, h1, sc, denom, (float*)d_out, E);
    }
    {
        size_t total = (size_t)N * OUT_F;
        post1_kernel<<<(unsigned)((total + 255) / 256), 256, 0, stream>>>(
            (float*)d_out, b1, total);
    }
}

// Round 2
// 848.203 us; speedup vs baseline: 2.0064x; 2.0064x over previous
//
#include <hip/hip_runtime.h>
#include <hip/hip_bf16.h>
#include <math.h>

#define IN_F 128
#define HID 64
#define HEADS 4
#define HD0 (HEADS * HID)   // 256
#define OUT_F 64
#define NOISE_SCALE 2.5372725354060904f

// ---------- GEMM: C[M,Nc] = A[M,K] @ B[K,Nc], row-major, fp32 ----------
#define BM 64
#define BN 64
#define BKT 16
#define TM 4
#define TN 4
__global__ __launch_bounds__(256) void gemm_kernel(
    const float* __restrict__ A, const float* __restrict__ B,
    float* __restrict__ C, int M, int K, int Nc) {
    __shared__ float As[BKT][BM + 1];
    __shared__ float Bs[BKT][BN + 1];
    int tid = threadIdx.x;
    int tx = tid % 16, ty = tid / 16;
    int row0 = blockIdx.y * BM;
    int col0 = blockIdx.x * BN;
    float acc[TM][TN] = {};
    for (int k0 = 0; k0 < K; k0 += BKT) {
        for (int i = tid; i < BM * BKT; i += 256) {
            int m = i / BKT, kk = i % BKT;
            int gm = row0 + m;
            As[kk][m] = (gm < M) ? A[(size_t)gm * K + (k0 + kk)] : 0.f;
        }
        for (int i = tid; i < BKT * BN; i += 256) {
            int kk = i / BN, n = i % BN;
            Bs[kk][n] = B[(size_t)(k0 + kk) * Nc + col0 + n];
        }
        __syncthreads();
#pragma unroll
        for (int kk = 0; kk < BKT; ++kk) {
            float a[TM], b[TN];
#pragma unroll
            for (int i = 0; i < TM; i++) a[i] = As[kk][ty * TM + i];
#pragma unroll
            for (int j = 0; j < TN; j++) b[j] = Bs[kk][tx * TN + j];
#pragma unroll
            for (int i = 0; i < TM; i++)
#pragma unroll
                for (int j = 0; j < TN; j++) acc[i][j] += a[i] * b[j];
        }
        __syncthreads();
    }
#pragma unroll
    for (int i = 0; i < TM; i++) {
        int gm = row0 + ty * TM + i;
        if (gm >= M) continue;
#pragma unroll
        for (int j = 0; j < TN; j++) {
            C[(size_t)gm * Nc + col0 + tx * TN + j] = acc[i][j];
        }
    }
}

// ---------- el/er: per (node, head) dot over D=64, one wave each ----------
template <int H>
__global__ __launch_bounds__(256) void eler_kernel(
    const float* __restrict__ h, const float* __restrict__ al,
    const float* __restrict__ ar, float* __restrict__ el,
    float* __restrict__ er, int N) {
    int gt = blockIdx.x * blockDim.x + threadIdx.x;
    int wave = gt >> 6;
    int lane = gt & 63;
    int n = wave / H, hd = wave % H;
    if (n >= N) return;
    float v = h[(size_t)n * (H * 64) + hd * 64 + lane];
    float a = v * al[hd * 64 + lane];
    float b = v * ar[hd * 64 + lane];
#pragma unroll
    for (int off = 32; off > 0; off >>= 1) {
        a += __shfl_down(a, off);
        b += __shfl_down(b, off);
    }
    if (lane == 0) {
        el[n * H + hd] = a;
        er[n * H + hd] = b;
    }
}

// ================= CSR build (dst-sorted, stores src directly) =================
__global__ __launch_bounds__(256) void degree_kernel(
    const int* __restrict__ dst, int* __restrict__ deg, int E) {
    int e = blockIdx.x * 256 + threadIdx.x;
    if (e < E) atomicAdd(&deg[dst[e]], 1);
}

// per-block exclusive scan; writes block total to bsum
__global__ __launch_bounds__(256) void scan_block_kernel(
    const int* __restrict__ deg, int* __restrict__ off,
    int* __restrict__ bsum, int N) {
    __shared__ int s[256];
    int i = blockIdx.x * 256 + threadIdx.x;
    int v = (i < N) ? deg[i] : 0;
    s[threadIdx.x] = v;
    __syncthreads();
    for (int d = 1; d < 256; d <<= 1) {
        int t = (threadIdx.x >= d) ? s[threadIdx.x - d] : 0;
        __syncthreads();
        s[threadIdx.x] += t;
        __syncthreads();
    }
    if (i < N) off[i] = s[threadIdx.x] - v;  // exclusive
    if (threadIdx.x == 255) bsum[blockIdx.x] = s[255];
}

// single-block exclusive scan of block sums (nb <= 512)
__global__ __launch_bounds__(512) void scan_partials_kernel(int* __restrict__ bsum, int nb) {
    __shared__ int s[512];
    int v = (threadIdx.x < nb) ? bsum[threadIdx.x] : 0;
    s[threadIdx.x] = v;
    __syncthreads();
    for (int d = 1; d < 512; d <<= 1) {
        int t = (threadIdx.x >= d) ? s[threadIdx.x - d] : 0;
        __syncthreads();
        s[threadIdx.x] += t;
        __syncthreads();
    }
    if (threadIdx.x < nb) bsum[threadIdx.x] = s[threadIdx.x] - v;  // exclusive
}

__global__ __launch_bounds__(256) void add_offsets_kernel(
    int* __restrict__ off, const int* __restrict__ bsum, int N, int E) {
    int i = blockIdx.x * 256 + threadIdx.x;
    if (i < N) off[i] += bsum[blockIdx.x];
    if (i == 0) off[N] = E;
}

__global__ __launch_bounds__(256) void fill_csr_kernel(
    const int* __restrict__ src, const int* __restrict__ dst,
    int* __restrict__ cur, int* __restrict__ csr_src, int E) {
    int e = blockIdx.x * 256 + threadIdx.x;
    if (e >= E) return;
    int d = dst[e];
    int pos = atomicAdd(&cur[d], 1);
    csr_src[pos] = src[e];
}

// ===== Layer 0 fused: online softmax + gather-agg + bias + leaky + noise =====
// one wave per node; lane owns features [lane*4, lane*4+4) (head = lane>>4)
__global__ __launch_bounds__(256) void agg0_kernel(
    const int* __restrict__ off, const int* __restrict__ csr_src,
    const float* __restrict__ h,      // [N,256]
    const float* __restrict__ el,     // [N,4]
    const float* __restrict__ er,     // [N,4]
    const float* __restrict__ b0,     // [256]
    const float* __restrict__ noise,  // [N,256]
    float* __restrict__ out, int N) {
    int gt = blockIdx.x * 256 + threadIdx.x;
    int n = gt >> 6;
    int lane = gt & 63;
    if (n >= N) return;
    int hd = lane >> 4;
    float er_n = er[n * 4 + hd];
    int beg = off[n], end = off[n + 1];
    float m = -INFINITY, l = 0.f;
    float ax = 0.f, ay = 0.f, az = 0.f, aw = 0.f;
    for (int p = beg; p < end; ++p) {
        int s = csr_src[p];
        float e = el[s * 4 + hd] + er_n;
        e = e > 0.f ? e : 0.2f * e;
        float mn = fmaxf(m, e);
        float c = __expf(m - mn);   // first iter: exp(-inf)=0
        float w = __expf(e - mn);
        const float4 hv = *(const float4*)(h + (size_t)s * HD0 + lane * 4);
        ax = ax * c + w * hv.x;
        ay = ay * c + w * hv.y;
        az = az * c + w * hv.z;
        aw = aw * c + w * hv.w;
        l = l * c + w;
        m = mn;
    }
    float inv = 1.f / l;  // l>0: self-loop guarantees >=1 edge
    const float4 bv = *(const float4*)(b0 + lane * 4);
    const float4 nv = *(const float4*)(noise + (size_t)n * HD0 + lane * 4);
    float4 o;
    o.x = ax * inv + bv.x; o.x = o.x > 0.f ? o.x : 0.01f * o.x; o.x += NOISE_SCALE * nv.x;
    o.y = ay * inv + bv.y; o.y = o.y > 0.f ? o.y : 0.01f * o.y; o.y += NOISE_SCALE * nv.y;
    o.z = az * inv + bv.z; o.z = o.z > 0.f ? o.z : 0.01f * o.z; o.z += NOISE_SCALE * nv.z;
    o.w = aw * inv + bv.w; o.w = o.w > 0.f ? o.w : 0.01f * o.w; o.w += NOISE_SCALE * nv.w;
    *(float4*)(out + (size_t)n * HD0 + lane * 4) = o;
}

// ===== Layer 1 fused: online softmax + gather-agg + bias (H=1, D=64) =====
__global__ __launch_bounds__(256) void agg1_kernel(
    const int* __restrict__ off, const int* __restrict__ csr_src,
    const float* __restrict__ h,     // [N,64]
    const float* __restrict__ el,    // [N]
    const float* __restrict__ er,    // [N]
    const float* __restrict__ b1,    // [64]
    float* __restrict__ out, int N) {
    int gt = blockIdx.x * 256 + threadIdx.x;
    int n = gt >> 6;
    int lane = gt & 63;
    if (n >= N) return;
    float er_n = er[n];
    int beg = off[n], end = off[n + 1];
    float m = -INFINITY, l = 0.f, acc = 0.f;
    for (int p = beg; p < end; ++p) {
        int s = csr_src[p];
        float e = el[s] + er_n;
        e = e > 0.f ? e : 0.2f * e;
        float mn = fmaxf(m, e);
        float c = __expf(m - mn);
        float w = __expf(e - mn);
        acc = acc * c + w * h[(size_t)s * 64 + lane];
        l = l * c + w;
        m = mn;
    }
    out[(size_t)n * 64 + lane] = acc / l + b1[lane];
}

extern "C" void kernel_launch(void* const* d_in, const int* in_sizes, int n_in,
                              void* d_out, int out_size, void* d_ws, size_t ws_size,
                              hipStream_t stream) {
    const float* x     = (const float*)d_in[0];
    const int*   src   = (const int*)d_in[1];
    const int*   dst   = (const int*)d_in[2];
    const float* W0    = (const float*)d_in[3];
    const float* al0   = (const float*)d_in[4];
    const float* ar0   = (const float*)d_in[5];
    const float* b0    = (const float*)d_in[6];
    const float* W1    = (const float*)d_in[7];
    const float* al1   = (const float*)d_in[8];
    const float* ar1   = (const float*)d_in[9];
    const float* b1    = (const float*)d_in[10];
    const float* noise = (const float*)d_in[11];

    const int N = in_sizes[0] / IN_F;   // 100000
    const int E = in_sizes[1];          // 900000
    const int NB = (N + 255) / 256;     // scan blocks (391, <=512)

    // Workspace layout
    float* ws   = (float*)d_ws;
    float* h0   = ws;                              // N*256 (aliased as h1)
    float* agg0 = h0 + (size_t)N * HD0;            // N*256
    float* el   = agg0 + (size_t)N * HD0;          // N*4
    float* er   = el + (size_t)N * HEADS;          // N*4
    int* deg    = (int*)(er + (size_t)N * HEADS);  // N
    int* cur    = deg + N;                         // N
    int* off    = cur + N;                         // N+1
    int* bsum   = off + (N + 1);                   // 512
    int* csr_src= bsum + 512;                      // E
    float* h1   = h0;

    // ---------- CSR build (shared by both layers) ----------
    hipMemsetAsync(deg, 0, (size_t)N * sizeof(int), stream);
    degree_kernel<<<(E + 255) / 256, 256, 0, stream>>>(dst, deg, E);
    scan_block_kernel<<<NB, 256, 0, stream>>>(deg, off, bsum, N);
    scan_partials_kernel<<<1, 512, 0, stream>>>(bsum, NB);
    add_offsets_kernel<<<NB, 256, 0, stream>>>(off, bsum, N, E);
    hipMemcpyAsync(cur, off, (size_t)N * sizeof(int), hipMemcpyDeviceToDevice, stream);
    fill_csr_kernel<<<(E + 255) / 256, 256, 0, stream>>>(src, dst, cur, csr_src, E);

    // ---------- Layer 0 ----------
    {
        dim3 grid(HD0 / BN, (N + BM - 1) / BM);
        gemm_kernel<<<grid, 256, 0, stream>>>(x, W0, h0, N, IN_F, HD0);
    }
    {
        int waves = N * HEADS;
        eler_kernel<HEADS><<<(waves * 64 + 255) / 256, 256, 0, stream>>>(h0, al0, ar0, el, er, N);
    }
    agg0_kernel<<<(N * 64 + 255) / 256, 256, 0, stream>>>(
        off, csr_src, h0, el, er, b0, noise, agg0, N);

    // ---------- Layer 1 ----------
    {
        dim3 grid(OUT_F / BN, (N + BM - 1) / BM);
        gemm_kernel<<<grid, 256, 0, stream>>>(agg0, W1, h1, N, HD0, OUT_F);
    }
    {
        int waves = N;
        eler_kernel<1><<<(waves * 64 + 255) / 256, 256, 0, stream>>>(h1, al1, ar1, el, er, N);
    }
    agg1_kernel<<<(N * 64 + 255) / 256, 256, 0, stream>>>(
        off, csr_src, h1, el, er, b1, (float*)d_out, N);
}

// Round 4
// 631.017 us; speedup vs baseline: 2.6969x; 1.3442x over previous
//
#include <hip/hip_runtime.h>
#include <hip/hip_bf16.h>
#include <math.h>

#define IN_F 128
#define HID 64
#define HEADS 4
#define HD0 (HEADS * HID)   // 256
#define OUT_F 64
#define NOISE_SCALE 2.5372725354060904f

typedef __bf16 bf16x8 __attribute__((ext_vector_type(8)));
typedef float f32x4 __attribute__((ext_vector_type(4)));

// ---------- bf16 helpers (raw ushort representation) ----------
__device__ __forceinline__ float bf2f(unsigned short u) {
    return __uint_as_float(((unsigned)u) << 16);
}
__device__ __forceinline__ unsigned short f2bf(float f) {
    unsigned u = __float_as_uint(f);
    u = u + 0x7fffu + ((u >> 16) & 1u);  // round-nearest-even
    return (unsigned short)(u >> 16);
}

// ---------- cast x fp32 -> bf16, 8 elems/thread ----------
__global__ __launch_bounds__(256) void cast_bf16_kernel(
    const float* __restrict__ in, unsigned short* __restrict__ out, size_t n8) {
    size_t i = (size_t)blockIdx.x * 256 + threadIdx.x;
    if (i >= n8) return;
    const float4 a = ((const float4*)in)[i * 2];
    const float4 b = ((const float4*)in)[i * 2 + 1];
    ushort4 o0, o1;
    o0.x = f2bf(a.x); o0.y = f2bf(a.y); o0.z = f2bf(a.z); o0.w = f2bf(a.w);
    o1.x = f2bf(b.x); o1.y = f2bf(b.y); o1.z = f2bf(b.z); o1.w = f2bf(b.w);
    ((ushort4*)out)[i * 2] = o0;
    ((ushort4*)out)[i * 2 + 1] = o1;
}

// ---------- transpose+cast W [K][NC] -> Wt [NC][K] bf16 ----------
__global__ __launch_bounds__(256) void tcast_kernel(
    const float* __restrict__ W, unsigned short* __restrict__ Wt, int K, int NC) {
    int i = blockIdx.x * 256 + threadIdx.x;
    if (i >= K * NC) return;
    int n = i / K, k = i % K;
    Wt[n * K + k] = f2bf(W[(size_t)k * NC + n]);
}

// ---------- MFMA GEMM: C[M,NC] = A[M,K] @ Bt[NC,K]^T, all bf16 ----------
// block = 4 waves, tile 128x64; Bt column block resident in LDS.
template <int K>
__global__ __launch_bounds__(256) void gemm_bf16_kernel(
    const unsigned short* __restrict__ A, const unsigned short* __restrict__ Bt,
    unsigned short* __restrict__ C, int M, int NC) {
    constexpr int BSTR = K + 8;   // Bs row stride (bf16 units)
    constexpr int ASTR = 40;      // As row stride for 32-wide k slab
    __shared__ __align__(16) unsigned short Bs[64 * BSTR];
    __shared__ __align__(16) unsigned short As[128 * ASTR];
    const int tid = threadIdx.x;
    const int lane = tid & 63, w = tid >> 6;
    const int row0 = blockIdx.y * 128;
    const int n0 = blockIdx.x * 64;
    // load B^T block [n0, n0+64) x K
    for (int i = tid; i < 64 * (K / 8); i += 256) {
        int n = i / (K / 8), kc = i % (K / 8);
        *(uint4*)(Bs + n * BSTR + kc * 8) =
            *(const uint4*)(Bt + (size_t)(n0 + n) * K + kc * 8);
    }
    f32x4 acc[2][4] = {};
    const int q = lane >> 4, c = lane & 15;
    // A staging: 2 threads per row, each covering 16 bf16 (two uint4s)
    const int r_st = tid >> 1, hh = tid & 1;
    for (int k0 = 0; k0 < K; k0 += 32) {
        int gr = row0 + r_st;
        uint4 av0 = make_uint4(0, 0, 0, 0), av1 = make_uint4(0, 0, 0, 0);
        if (gr < M) {
            const unsigned short* ap = A + (size_t)gr * K + k0 + hh * 16;
            av0 = *(const uint4*)(ap);
            av1 = *(const uint4*)(ap + 8);
        }
        __syncthreads();   // prev-iter frag reads done before overwrite
        *(uint4*)(As + r_st * ASTR + hh * 16) = av0;
        *(uint4*)(As + r_st * ASTR + hh * 16 + 8) = av1;
        __syncthreads();
        bf16x8 af[2], bfr[4];
        af[0] = *(const bf16x8*)(As + (w * 32 + c) * ASTR + q * 8);
        af[1] = *(const bf16x8*)(As + (w * 32 + 16 + c) * ASTR + q * 8);
#pragma unroll
        for (int nt = 0; nt < 4; ++nt)
            bfr[nt] = *(const bf16x8*)(Bs + (nt * 16 + c) * BSTR + k0 + q * 8);
#pragma unroll
        for (int mt = 0; mt < 2; ++mt)
#pragma unroll
            for (int nt = 0; nt < 4; ++nt)
                acc[mt][nt] = __builtin_amdgcn_mfma_f32_16x16x32_bf16(
                    af[mt], bfr[nt], acc[mt][nt], 0, 0, 0);
    }
    // epilogue: C/D layout col=lane&15, row=q*4+reg
#pragma unroll
    for (int mt = 0; mt < 2; ++mt) {
#pragma unroll
        for (int r = 0; r < 4; ++r) {
            int grow = row0 + w * 32 + mt * 16 + q * 4 + r;
            if (grow >= M) continue;
#pragma unroll
            for (int nt = 0; nt < 4; ++nt)
                C[(size_t)grow * NC + n0 + nt * 16 + c] = f2bf(acc[mt][nt][r]);
        }
    }
}

// ---------- el/er from bf16 h ----------
template <int H>
__global__ __launch_bounds__(256) void eler_kernel(
    const unsigned short* __restrict__ h, const float* __restrict__ al,
    const float* __restrict__ ar, float* __restrict__ el,
    float* __restrict__ er, int N) {
    int gt = blockIdx.x * blockDim.x + threadIdx.x;
    int wave = gt >> 6;
    int lane = gt & 63;
    int n = wave / H, hd = wave % H;
    if (n >= N) return;
    float v = bf2f(h[(size_t)n * (H * 64) + hd * 64 + lane]);
    float a = v * al[hd * 64 + lane];
    float b = v * ar[hd * 64 + lane];
#pragma unroll
    for (int off = 32; off > 0; off >>= 1) {
        a += __shfl_down(a, off);
        b += __shfl_down(b, off);
    }
    if (lane == 0) {
        el[n * H + hd] = a;
        er[n * H + hd] = b;
    }
}

// ================= CSR build =================
__global__ __launch_bounds__(256) void degree_kernel(
    const int* __restrict__ dst, int* __restrict__ deg, int E) {
    int e = blockIdx.x * 256 + threadIdx.x;
    if (e < E) atomicAdd(&deg[dst[e]], 1);
}

__global__ __launch_bounds__(256) void scan_block_kernel(
    const int* __restrict__ deg, int* __restrict__ off,
    int* __restrict__ bsum, int N) {
    __shared__ int s[256];
    int i = blockIdx.x * 256 + threadIdx.x;
    int v = (i < N) ? deg[i] : 0;
    s[threadIdx.x] = v;
    __syncthreads();
    for (int d = 1; d < 256; d <<= 1) {
        int t = (threadIdx.x >= d) ? s[threadIdx.x - d] : 0;
        __syncthreads();
        s[threadIdx.x] += t;
        __syncthreads();
    }
    if (i < N) off[i] = s[threadIdx.x] - v;
    if (threadIdx.x == 255) bsum[blockIdx.x] = s[255];
}

__global__ __launch_bounds__(512) void scan_partials_kernel(int* __restrict__ bsum, int nb) {
    __shared__ int s[512];
    int v = (threadIdx.x < nb) ? bsum[threadIdx.x] : 0;
    s[threadIdx.x] = v;
    __syncthreads();
    for (int d = 1; d < 512; d <<= 1) {
        int t = (threadIdx.x >= d) ? s[threadIdx.x - d] : 0;
        __syncthreads();
        s[threadIdx.x] += t;
        __syncthreads();
    }
    if (threadIdx.x < nb) bsum[threadIdx.x] = s[threadIdx.x] - v;
}

__global__ __launch_bounds__(256) void add_offsets_kernel(
    int* __restrict__ off, const int* __restrict__ bsum, int N, int E) {
    int i = blockIdx.x * 256 + threadIdx.x;
    if (i < N) off[i] += bsum[blockIdx.x];
    if (i == 0) off[N] = E;
}

__global__ __launch_bounds__(256) void fill_csr_kernel(
    const int* __restrict__ src, const int* __restrict__ dst,
    int* __restrict__ cur, int* __restrict__ csr_src, int E) {
    int e = blockIdx.x * 256 + threadIdx.x;
    if (e >= E) return;
    int d = dst[e];
    int pos = atomicAdd(&cur[d], 1);
    csr_src[pos] = src[e];
}

// ===== Layer 0 fused: online softmax + gather (bf16) + bias + leaky + noise -> bf16 =====
__global__ __launch_bounds__(256) void agg0_kernel(
    const int* __restrict__ off, const int* __restrict__ csr_src,
    const unsigned short* __restrict__ h,   // [N,256] bf16
    const float* __restrict__ el, const float* __restrict__ er,
    const float* __restrict__ b0, const float* __restrict__ noise,
    unsigned short* __restrict__ out, int N) {
    int gt = blockIdx.x * 256 + threadIdx.x;
    int n = gt >> 6;
    int lane = gt & 63;
    if (n >= N) return;
    int hd = lane >> 4;
    float er_n = er[n * 4 + hd];
    int beg = off[n], end = off[n + 1];
    float m = -INFINITY, l = 0.f;
    float ax = 0.f, ay = 0.f, az = 0.f, aw = 0.f;
    for (int p = beg; p < end; ++p) {
        int s = csr_src[p];
        float e = el[s * 4 + hd] + er_n;
        e = e > 0.f ? e : 0.2f * e;
        float mn = fmaxf(m, e);
        float cs = __expf(m - mn);
        float wt = __expf(e - mn);
        ushort4 hv = *(const ushort4*)(h + (size_t)s * HD0 + lane * 4);
        ax = ax * cs + wt * bf2f(hv.x);
        ay = ay * cs + wt * bf2f(hv.y);
        az = az * cs + wt * bf2f(hv.z);
        aw = aw * cs + wt * bf2f(hv.w);
        l = l * cs + wt;
        m = mn;
    }
    float inv = 1.f / l;
    const float4 bv = *(const float4*)(b0 + lane * 4);
    const float4 nv = *(const float4*)(noise + (size_t)n * HD0 + lane * 4);
    float ox = ax * inv + bv.x; ox = ox > 0.f ? ox : 0.01f * ox; ox += NOISE_SCALE * nv.x;
    float oy = ay * inv + bv.y; oy = oy > 0.f ? oy : 0.01f * oy; oy += NOISE_SCALE * nv.y;
    float oz = az * inv + bv.z; oz = oz > 0.f ? oz : 0.01f * oz; oz += NOISE_SCALE * nv.z;
    float ow = aw * inv + bv.w; ow = ow > 0.f ? ow : 0.01f * ow; ow += NOISE_SCALE * nv.w;
    ushort4 o;
    o.x = f2bf(ox); o.y = f2bf(oy); o.z = f2bf(oz); o.w = f2bf(ow);
    *(ushort4*)(out + (size_t)n * HD0 + lane * 4) = o;
}

// ===== Layer 1 fused: online softmax + gather (bf16) + bias -> fp32 out =====
__global__ __launch_bounds__(256) void agg1_kernel(
    const int* __restrict__ off, const int* __restrict__ csr_src,
    const unsigned short* __restrict__ h,   // [N,64] bf16
    const float* __restrict__ el, const float* __restrict__ er,
    const float* __restrict__ b1, float* __restrict__ out, int N) {
    int gt = blockIdx.x * 256 + threadIdx.x;
    int n = gt >> 6;
    int lane = gt & 63;
    if (n >= N) return;
    float er_n = er[n];
    int beg = off[n], end = off[n + 1];
    float m = -INFINITY, l = 0.f, acc = 0.f;
    for (int p = beg; p < end; ++p) {
        int s = csr_src[p];
        float e = el[s] + er_n;
        e = e > 0.f ? e : 0.2f * e;
        float mn = fmaxf(m, e);
        float cs = __expf(m - mn);
        float wt = __expf(e - mn);
        acc = acc * cs + wt * bf2f(h[(size_t)s * 64 + lane]);
        l = l * cs + wt;
        m = mn;
    }
    out[(size_t)n * 64 + lane] = acc / l + b1[lane];
}

extern "C" void kernel_launch(void* const* d_in, const int* in_sizes, int n_in,
                              void* d_out, int out_size, void* d_ws, size_t ws_size,
                              hipStream_t stream) {
    const float* x     = (const float*)d_in[0];
    const int*   src   = (const int*)d_in[1];
    const int*   dst   = (const int*)d_in[2];
    const float* W0    = (const float*)d_in[3];
    const float* al0   = (const float*)d_in[4];
    const float* ar0   = (const float*)d_in[5];
    const float* b0    = (const float*)d_in[6];
    const float* W1    = (const float*)d_in[7];
    const float* al1   = (const float*)d_in[8];
    const float* ar1   = (const float*)d_in[9];
    const float* b1    = (const float*)d_in[10];
    const float* noise = (const float*)d_in[11];

    const int N = in_sizes[0] / IN_F;   // 100000
    const int E = in_sizes[1];          // 900000
    const int NB = (N + 255) / 256;

    // Workspace layout (bytes, 16B-aligned chunks)
    char* p = (char*)d_ws;
    unsigned short* x_bf  = (unsigned short*)p; p += (size_t)N * IN_F * 2;
    unsigned short* h0    = (unsigned short*)p; p += (size_t)N * HD0 * 2;
    unsigned short* agg0  = (unsigned short*)p; p += (size_t)N * HD0 * 2;
    unsigned short* h1    = (unsigned short*)p; p += (size_t)N * OUT_F * 2;
    unsigned short* W0t   = (unsigned short*)p; p += (size_t)IN_F * HD0 * 2;
    unsigned short* W1t   = (unsigned short*)p; p += (size_t)HD0 * OUT_F * 2;
    float* el   = (float*)p; p += (size_t)N * HEADS * 4;
    float* er   = (float*)p; p += (size_t)N * HEADS * 4;
    int* deg    = (int*)p; p += (size_t)N * 4;
    int* cur    = (int*)p; p += (size_t)N * 4;
    int* off    = (int*)p; p += ((size_t)N + 4) * 4;
    int* bsum   = (int*)p; p += 512 * 4;
    int* csr_src= (int*)p; p += (size_t)E * 4;

    // ---------- casts ----------
    {
        size_t n8 = (size_t)N * IN_F / 8;
        cast_bf16_kernel<<<(unsigned)((n8 + 255) / 256), 256, 0, stream>>>(x, x_bf, n8);
    }
    tcast_kernel<<<(IN_F * HD0 + 255) / 256, 256, 0, stream>>>(W0, W0t, IN_F, HD0);
    tcast_kernel<<<(HD0 * OUT_F + 255) / 256, 256, 0, stream>>>(W1, W1t, HD0, OUT_F);

    // ---------- CSR build ----------
    hipMemsetAsync(deg, 0, (size_t)N * sizeof(int), stream);
    degree_kernel<<<(E + 255) / 256, 256, 0, stream>>>(dst, deg, E);
    scan_block_kernel<<<NB, 256, 0, stream>>>(deg, off, bsum, N);
    scan_partials_kernel<<<1, 512, 0, stream>>>(bsum, NB);
    add_offsets_kernel<<<NB, 256, 0, stream>>>(off, bsum, N, E);
    hipMemcpyAsync(cur, off, (size_t)N * sizeof(int), hipMemcpyDeviceToDevice, stream);
    fill_csr_kernel<<<(E + 255) / 256, 256, 0, stream>>>(src, dst, cur, csr_src, E);

    const int MB = (N + 127) / 128;   // 782

    // ---------- Layer 0 ----------
    {
        dim3 grid(HD0 / 64, MB);
        gemm_bf16_kernel<IN_F><<<grid, 256, 0, stream>>>(x_bf, W0t, h0, N, HD0);
    }
    eler_kernel<HEADS><<<(N * HEADS * 64 + 255) / 256, 256, 0, stream>>>(
        h0, al0, ar0, el, er, N);
    agg0_kernel<<<(N * 64 + 255) / 256, 256, 0, stream>>>(
        off, csr_src, h0, el, er, b0, noise, agg0, N);

    // ---------- Layer 1 ----------
    {
        dim3 grid(OUT_F / 64, MB);
        gemm_bf16_kernel<HD0><<<grid, 256, 0, stream>>>(agg0, W1t, h1, N, OUT_F);
    }
    eler_kernel<1><<<(N * 64 + 255) / 256, 256, 0, stream>>>(h1, al1, ar1, el, er, N);
    agg1_kernel<<<(N * 64 + 255) / 256, 256, 0, stream>>>(
        off, csr_src, h1, el, er, b1, (float*)d_out, N);
}

// Round 5
// 526.152 us; speedup vs baseline: 3.2345x; 1.1993x over previous
//
#include <hip/hip_runtime.h>
#include <hip/hip_bf16.h>
#include <math.h>

#define IN_F 128
#define HID 64
#define HEADS 4
#define HD0 (HEADS * HID)   // 256
#define OUT_F 64
#define NOISE_SCALE 2.5372725354060904f

typedef __bf16 bf16x8 __attribute__((ext_vector_type(8)));
typedef float f32x4 __attribute__((ext_vector_type(4)));

__device__ __forceinline__ float bf2f(unsigned short u) {
    return __uint_as_float(((unsigned)u) << 16);
}
__device__ __forceinline__ unsigned short f2bf(float f) {
    unsigned u = __float_as_uint(f);
    u = u + 0x7fffu + ((u >> 16) & 1u);  // round-nearest-even
    return (unsigned short)(u >> 16);
}

// ---------- transpose+cast W [K][NC] -> Wt [NC][K] bf16 ----------
__global__ __launch_bounds__(256) void tcast_kernel(
    const float* __restrict__ W, unsigned short* __restrict__ Wt, int K, int NC) {
    int i = blockIdx.x * 256 + threadIdx.x;
    if (i >= K * NC) return;
    int n = i / K, k = i % K;
    Wt[n * K + k] = f2bf(W[(size_t)k * NC + n]);
}

// ---------- MFMA GEMM + fused el/er epilogue ----------
// C[M,NC] = A[M,K] @ Bt[NC,K]^T. If CASTA, A is fp32 (cast during staging).
// Epilogue also computes el[row,head] = sum_col h*al, er likewise, where
// head = n0>>6 (each 64-col block is exactly one head).
template <int K, bool CASTA, int H>
__global__ __launch_bounds__(256) void gemm_fused_kernel(
    const void* __restrict__ Av, const unsigned short* __restrict__ Bt,
    unsigned short* __restrict__ C, const float* __restrict__ al,
    const float* __restrict__ ar, float* __restrict__ el,
    float* __restrict__ er, int M, int NC) {
    constexpr int BSTR = K + 8;
    constexpr int ASTR = 40;
    __shared__ __align__(16) unsigned short Bs[64 * BSTR];
    __shared__ __align__(16) unsigned short As[128 * ASTR];
    const int tid = threadIdx.x;
    const int lane = tid & 63, w = tid >> 6;
    const int row0 = blockIdx.y * 128;
    const int n0 = blockIdx.x * 64;
    for (int i = tid; i < 64 * (K / 8); i += 256) {
        int n = i / (K / 8), kc = i % (K / 8);
        *(uint4*)(Bs + n * BSTR + kc * 8) =
            *(const uint4*)(Bt + (size_t)(n0 + n) * K + kc * 8);
    }
    f32x4 acc[2][4] = {};
    const int q = lane >> 4, c = lane & 15;
    const int r_st = tid >> 1, hh = tid & 1;
    for (int k0 = 0; k0 < K; k0 += 32) {
        int gr = row0 + r_st;
        uint4 av0 = make_uint4(0, 0, 0, 0), av1 = make_uint4(0, 0, 0, 0);
        if (gr < M) {
            if (CASTA) {
                const float* A = (const float*)Av;
                const float* ap = A + (size_t)gr * K + k0 + hh * 16;
                float4 f0 = *(const float4*)(ap);
                float4 f1 = *(const float4*)(ap + 4);
                float4 f2 = *(const float4*)(ap + 8);
                float4 f3 = *(const float4*)(ap + 12);
                ushort4 u0, u1, u2, u3;
                u0.x = f2bf(f0.x); u0.y = f2bf(f0.y); u0.z = f2bf(f0.z); u0.w = f2bf(f0.w);
                u1.x = f2bf(f1.x); u1.y = f2bf(f1.y); u1.z = f2bf(f1.z); u1.w = f2bf(f1.w);
                u2.x = f2bf(f2.x); u2.y = f2bf(f2.y); u2.z = f2bf(f2.z); u2.w = f2bf(f2.w);
                u3.x = f2bf(f3.x); u3.y = f2bf(f3.y); u3.z = f2bf(f3.z); u3.w = f2bf(f3.w);
                av0 = make_uint4(((unsigned)u0.y << 16) | u0.x, ((unsigned)u0.w << 16) | u0.z,
                                 ((unsigned)u1.y << 16) | u1.x, ((unsigned)u1.w << 16) | u1.z);
                av1 = make_uint4(((unsigned)u2.y << 16) | u2.x, ((unsigned)u2.w << 16) | u2.z,
                                 ((unsigned)u3.y << 16) | u3.x, ((unsigned)u3.w << 16) | u3.z);
            } else {
                const unsigned short* A = (const unsigned short*)Av;
                const unsigned short* ap = A + (size_t)gr * K + k0 + hh * 16;
                av0 = *(const uint4*)(ap);
                av1 = *(const uint4*)(ap + 8);
            }
        }
        __syncthreads();
        *(uint4*)(As + r_st * ASTR + hh * 16) = av0;
        *(uint4*)(As + r_st * ASTR + hh * 16 + 8) = av1;
        __syncthreads();
        bf16x8 af[2], bfr[4];
        af[0] = *(const bf16x8*)(As + (w * 32 + c) * ASTR + q * 8);
        af[1] = *(const bf16x8*)(As + (w * 32 + 16 + c) * ASTR + q * 8);
#pragma unroll
        for (int nt = 0; nt < 4; ++nt)
            bfr[nt] = *(const bf16x8*)(Bs + (nt * 16 + c) * BSTR + k0 + q * 8);
#pragma unroll
        for (int mt = 0; mt < 2; ++mt)
#pragma unroll
            for (int nt = 0; nt < 4; ++nt)
                acc[mt][nt] = __builtin_amdgcn_mfma_f32_16x16x32_bf16(
                    af[mt], bfr[nt], acc[mt][nt], 0, 0, 0);
    }
    // epilogue: C store + fused el/er (C/D layout: col=c, row=q*4+r)
    float alv[4], arv[4];
#pragma unroll
    for (int nt = 0; nt < 4; ++nt) {
        alv[nt] = al[n0 + nt * 16 + c];
        arv[nt] = ar[n0 + nt * 16 + c];
    }
    const int head = n0 >> 6;
#pragma unroll
    for (int mt = 0; mt < 2; ++mt) {
#pragma unroll
        for (int r = 0; r < 4; ++r) {
            int grow = row0 + w * 32 + mt * 16 + q * 4 + r;
            bool ok = grow < M;
            float elp = 0.f, erp = 0.f;
#pragma unroll
            for (int nt = 0; nt < 4; ++nt) {
                float v = acc[mt][nt][r];
                elp += v * alv[nt];
                erp += v * arv[nt];
                if (ok) C[(size_t)grow * NC + n0 + nt * 16 + c] = f2bf(v);
            }
#pragma unroll
            for (int o = 8; o > 0; o >>= 1) {
                elp += __shfl_down(elp, o, 16);
                erp += __shfl_down(erp, o, 16);
            }
            if (c == 0 && ok) {
                el[(size_t)grow * H + head] = elp;
                er[(size_t)grow * H + head] = erp;
            }
        }
    }
}

// ================= CSR build =================
__global__ __launch_bounds__(256) void degree_kernel(
    const int* __restrict__ dst, int* __restrict__ deg, int E) {
    int e = blockIdx.x * 256 + threadIdx.x;
    if (e < E) atomicAdd(&deg[dst[e]], 1);
}

__global__ __launch_bounds__(256) void scan_block_kernel(
    const int* __restrict__ deg, int* __restrict__ off,
    int* __restrict__ bsum, int N) {
    __shared__ int s[256];
    int i = blockIdx.x * 256 + threadIdx.x;
    int v = (i < N) ? deg[i] : 0;
    s[threadIdx.x] = v;
    __syncthreads();
    for (int d = 1; d < 256; d <<= 1) {
        int t = (threadIdx.x >= d) ? s[threadIdx.x - d] : 0;
        __syncthreads();
        s[threadIdx.x] += t;
        __syncthreads();
    }
    if (i < N) off[i] = s[threadIdx.x] - v;
    if (threadIdx.x == 255) bsum[blockIdx.x] = s[255];
}

__global__ __launch_bounds__(512) void scan_partials_kernel(int* __restrict__ bsum, int nb) {
    __shared__ int s[512];
    int v = (threadIdx.x < nb) ? bsum[threadIdx.x] : 0;
    s[threadIdx.x] = v;
    __syncthreads();
    for (int d = 1; d < 512; d <<= 1) {
        int t = (threadIdx.x >= d) ? s[threadIdx.x - d] : 0;
        __syncthreads();
        s[threadIdx.x] += t;
        __syncthreads();
    }
    if (threadIdx.x < nb) bsum[threadIdx.x] = s[threadIdx.x] - v;
}

__global__ __launch_bounds__(256) void add_offsets_kernel(
    int* __restrict__ off, const int* __restrict__ bsum, int N, int E) {
    int i = blockIdx.x * 256 + threadIdx.x;
    if (i < N) off[i] += bsum[blockIdx.x];
    if (i == 0) off[N] = E;
}

__global__ __launch_bounds__(256) void fill_csr_kernel(
    const int* __restrict__ src, const int* __restrict__ dst,
    int* __restrict__ cur, int* __restrict__ csr_src, int E) {
    int e = blockIdx.x * 256 + threadIdx.x;
    if (e >= E) return;
    int d = dst[e];
    int pos = atomicAdd(&cur[d], 1);
    csr_src[pos] = src[e];
}

// ---------- per-edge softmax weights: alpha=exp(e-max), rden=1/sum ----------
// one thread per (node, head); el table is small -> L2-hit gathers
template <int H>
__global__ __launch_bounds__(256) void alpha_kernel(
    const int* __restrict__ off, const int* __restrict__ csr_src,
    const float* __restrict__ el, const float* __restrict__ er,
    float* __restrict__ alpha, float* __restrict__ rden, int N) {
    int t = blockIdx.x * 256 + threadIdx.x;
    int n = t / H, hd = t % H;
    if (n >= N) return;
    float ern = er[(size_t)n * H + hd];
    int beg = off[n], end = off[n + 1];
    float m = -INFINITY;
    for (int p = beg; p < end; ++p) {
        float e = el[(size_t)csr_src[p] * H + hd] + ern;
        e = e > 0.f ? e : 0.2f * e;
        m = fmaxf(m, e);
    }
    float l = 0.f;
    for (int p = beg; p < end; ++p) {
        float e = el[(size_t)csr_src[p] * H + hd] + ern;
        e = e > 0.f ? e : 0.2f * e;
        float wv = __expf(e - m);
        alpha[(size_t)p * H + hd] = wv;
        l += wv;
    }
    rden[(size_t)n * H + hd] = 1.f / l;
}

// ===== Layer 0 gather: pure weighted FMA + bias + leaky + noise -> bf16 =====
__global__ __launch_bounds__(256) void agg0_kernel(
    const int* __restrict__ off, const int* __restrict__ csr_src,
    const unsigned short* __restrict__ h,   // [N,256] bf16
    const float* __restrict__ alpha,        // [E,4]
    const float* __restrict__ rden,         // [N,4]
    const float* __restrict__ b0, const float* __restrict__ noise,
    unsigned short* __restrict__ out, int N) {
    int gt = blockIdx.x * 256 + threadIdx.x;
    int n = gt >> 6;
    int lane = gt & 63;
    if (n >= N) return;
    int hd = lane >> 4;
    int beg = off[n], end = off[n + 1];
    float ax = 0.f, ay = 0.f, az = 0.f, aw = 0.f;
    int p = beg;
    for (; p + 2 <= end; p += 2) {
        int s0 = csr_src[p], s1 = csr_src[p + 1];
        float w0 = alpha[(size_t)p * 4 + hd];
        float w1 = alpha[(size_t)(p + 1) * 4 + hd];
        ushort4 u0 = *(const ushort4*)(h + (size_t)s0 * HD0 + lane * 4);
        ushort4 u1 = *(const ushort4*)(h + (size_t)s1 * HD0 + lane * 4);
        ax += w0 * bf2f(u0.x) + w1 * bf2f(u1.x);
        ay += w0 * bf2f(u0.y) + w1 * bf2f(u1.y);
        az += w0 * bf2f(u0.z) + w1 * bf2f(u1.z);
        aw += w0 * bf2f(u0.w) + w1 * bf2f(u1.w);
    }
    if (p < end) {
        int s0 = csr_src[p];
        float w0 = alpha[(size_t)p * 4 + hd];
        ushort4 u0 = *(const ushort4*)(h + (size_t)s0 * HD0 + lane * 4);
        ax += w0 * bf2f(u0.x);
        ay += w0 * bf2f(u0.y);
        az += w0 * bf2f(u0.z);
        aw += w0 * bf2f(u0.w);
    }
    float rd = rden[(size_t)n * 4 + hd];
    const float4 bv = *(const float4*)(b0 + lane * 4);
    const float4 nv = *(const float4*)(noise + (size_t)n * HD0 + lane * 4);
    float ox = ax * rd + bv.x; ox = ox > 0.f ? ox : 0.01f * ox; ox += NOISE_SCALE * nv.x;
    float oy = ay * rd + bv.y; oy = oy > 0.f ? oy : 0.01f * oy; oy += NOISE_SCALE * nv.y;
    float oz = az * rd + bv.z; oz = oz > 0.f ? oz : 0.01f * oz; oz += NOISE_SCALE * nv.z;
    float ow = aw * rd + bv.w; ow = ow > 0.f ? ow : 0.01f * ow; ow += NOISE_SCALE * nv.w;
    ushort4 o;
    o.x = f2bf(ox); o.y = f2bf(oy); o.z = f2bf(oz); o.w = f2bf(ow);
    *(ushort4*)(out + (size_t)n * HD0 + lane * 4) = o;
}

// ===== Layer 1 gather: pure weighted FMA + bias -> fp32 =====
__global__ __launch_bounds__(256) void agg1_kernel(
    const int* __restrict__ off, const int* __restrict__ csr_src,
    const unsigned short* __restrict__ h,   // [N,64] bf16
    const float* __restrict__ alpha,        // [E]
    const float* __restrict__ rden,         // [N]
    const float* __restrict__ b1, float* __restrict__ out, int N) {
    int gt = blockIdx.x * 256 + threadIdx.x;
    int n = gt >> 6;
    int lane = gt & 63;
    if (n >= N) return;
    int beg = off[n], end = off[n + 1];
    float acc = 0.f;
    int p = beg;
    for (; p + 4 <= end; p += 4) {
        int s0 = csr_src[p], s1 = csr_src[p + 1], s2 = csr_src[p + 2], s3 = csr_src[p + 3];
        float w0 = alpha[p], w1 = alpha[p + 1], w2 = alpha[p + 2], w3 = alpha[p + 3];
        float v0 = bf2f(h[(size_t)s0 * 64 + lane]);
        float v1 = bf2f(h[(size_t)s1 * 64 + lane]);
        float v2 = bf2f(h[(size_t)s2 * 64 + lane]);
        float v3 = bf2f(h[(size_t)s3 * 64 + lane]);
        acc += w0 * v0 + w1 * v1 + w2 * v2 + w3 * v3;
    }
    for (; p < end; ++p) {
        acc += alpha[p] * bf2f(h[(size_t)csr_src[p] * 64 + lane]);
    }
    out[(size_t)n * 64 + lane] = acc * rden[n] + b1[lane];
}

extern "C" void kernel_launch(void* const* d_in, const int* in_sizes, int n_in,
                              void* d_out, int out_size, void* d_ws, size_t ws_size,
                              hipStream_t stream) {
    const float* x     = (const float*)d_in[0];
    const int*   src   = (const int*)d_in[1];
    const int*   dst   = (const int*)d_in[2];
    const float* W0    = (const float*)d_in[3];
    const float* al0   = (const float*)d_in[4];
    const float* ar0   = (const float*)d_in[5];
    const float* b0    = (const float*)d_in[6];
    const float* W1    = (const float*)d_in[7];
    const float* al1   = (const float*)d_in[8];
    const float* ar1   = (const float*)d_in[9];
    const float* b1    = (const float*)d_in[10];
    const float* noise = (const float*)d_in[11];

    const int N = in_sizes[0] / IN_F;   // 100000
    const int E = in_sizes[1];          // 900000
    const int NB = (N + 255) / 256;

    // Workspace layout
    char* p = (char*)d_ws;
    unsigned short* h0     = (unsigned short*)p; p += (size_t)N * HD0 * 2;
    unsigned short* agg0b  = (unsigned short*)p; p += (size_t)N * HD0 * 2;
    unsigned short* h1     = (unsigned short*)p; p += (size_t)N * OUT_F * 2;
    unsigned short* W0t    = (unsigned short*)p; p += (size_t)IN_F * HD0 * 2;
    unsigned short* W1t    = (unsigned short*)p; p += (size_t)HD0 * OUT_F * 2;
    float* el     = (float*)p; p += (size_t)N * HEADS * 4;
    float* er     = (float*)p; p += (size_t)N * HEADS * 4;
    float* alpha0 = (float*)p; p += (size_t)E * HEADS * 4;
    float* rden0  = (float*)p; p += (size_t)N * HEADS * 4;
    float* alpha1 = (float*)p; p += (size_t)E * 4;
    float* rden1  = (float*)p; p += (size_t)N * 4;
    int* deg    = (int*)p; p += (size_t)N * 4;
    int* cur    = (int*)p; p += (size_t)N * 4;
    int* off    = (int*)p; p += ((size_t)N + 4) * 4;
    int* bsum   = (int*)p; p += 512 * 4;
    int* csr_src= (int*)p; p += (size_t)E * 4;

    // ---------- weight transposes ----------
    tcast_kernel<<<(IN_F * HD0 + 255) / 256, 256, 0, stream>>>(W0, W0t, IN_F, HD0);
    tcast_kernel<<<(HD0 * OUT_F + 255) / 256, 256, 0, stream>>>(W1, W1t, HD0, OUT_F);

    // ---------- CSR build ----------
    hipMemsetAsync(deg, 0, (size_t)N * sizeof(int), stream);
    degree_kernel<<<(E + 255) / 256, 256, 0, stream>>>(dst, deg, E);
    scan_block_kernel<<<NB, 256, 0, stream>>>(deg, off, bsum, N);
    scan_partials_kernel<<<1, 512, 0, stream>>>(bsum, NB);
    add_offsets_kernel<<<NB, 256, 0, stream>>>(off, bsum, N, E);
    hipMemcpyAsync(cur, off, (size_t)N * sizeof(int), hipMemcpyDeviceToDevice, stream);
    fill_csr_kernel<<<(E + 255) / 256, 256, 0, stream>>>(src, dst, cur, csr_src, E);

    const int MB = (N + 127) / 128;   // 782

    // ---------- Layer 0 ----------
    {
        dim3 grid(HD0 / 64, MB);
        gemm_fused_kernel<IN_F, true, HEADS><<<grid, 256, 0, stream>>>(
            x, W0t, h0, al0, ar0, el, er, N, HD0);
    }
    alpha_kernel<HEADS><<<(N * HEADS + 255) / 256, 256, 0, stream>>>(
        off, csr_src, el, er, alpha0, rden0, N);
    agg0_kernel<<<(N * 64 + 255) / 256, 256, 0, stream>>>(
        off, csr_src, h0, alpha0, rden0, b0, noise, agg0b, N);

    // ---------- Layer 1 ----------
    {
        dim3 grid(OUT_F / 64, MB);
        gemm_fused_kernel<HD0, false, 1><<<grid, 256, 0, stream>>>(
            agg0b, W1t, h1, al1, ar1, el, er, N, OUT_F);
    }
    alpha_kernel<1><<<(N + 255) / 256, 256, 0, stream>>>(
        off, csr_src, el, er, alpha1, rden1, N);
    agg1_kernel<<<(N * 64 + 255) / 256, 256, 0, stream>>>(
        off, csr_src, h1, alpha1, rden1, b1, (float*)d_out, N);
}

// Round 6
// 502.514 us; speedup vs baseline: 3.3866x; 1.0470x over previous
//
#include <hip/hip_runtime.h>
#include <hip/hip_bf16.h>
#include <math.h>

#define IN_F 128
#define HID 64
#define HEADS 4
#define HD0 (HEADS * HID)   // 256
#define OUT_F 64
#define NOISE_SCALE 2.5372725354060904f

typedef __bf16 bf16x8 __attribute__((ext_vector_type(8)));
typedef float f32x4 __attribute__((ext_vector_type(4)));

__device__ __forceinline__ float bf2f(unsigned short u) {
    return __uint_as_float(((unsigned)u) << 16);
}
__device__ __forceinline__ unsigned short f2bf(float f) {
    unsigned u = __float_as_uint(f);
    u = u + 0x7fffu + ((u >> 16) & 1u);  // round-nearest-even
    return (unsigned short)(u >> 16);
}

// ---------- transpose+cast W [K][NC] -> Wt [NC][K] bf16 ----------
__global__ __launch_bounds__(256) void tcast_kernel(
    const float* __restrict__ W, unsigned short* __restrict__ Wt, int K, int NC) {
    int i = blockIdx.x * 256 + threadIdx.x;
    if (i >= K * NC) return;
    int n = i / K, k = i % K;
    Wt[n * K + k] = f2bf(W[(size_t)k * NC + n]);
}

// ---------- MFMA GEMM + fused el/er epilogue ----------
template <int K, bool CASTA, int H>
__global__ __launch_bounds__(256) void gemm_fused_kernel(
    const void* __restrict__ Av, const unsigned short* __restrict__ Bt,
    unsigned short* __restrict__ C, const float* __restrict__ al,
    const float* __restrict__ ar, float* __restrict__ el,
    float* __restrict__ er, int M, int NC) {
    constexpr int BSTR = K + 8;
    constexpr int ASTR = 40;
    __shared__ __align__(16) unsigned short Bs[64 * BSTR];
    __shared__ __align__(16) unsigned short As[128 * ASTR];
    const int tid = threadIdx.x;
    const int lane = tid & 63, w = tid >> 6;
    const int row0 = blockIdx.y * 128;
    const int n0 = blockIdx.x * 64;
    for (int i = tid; i < 64 * (K / 8); i += 256) {
        int n = i / (K / 8), kc = i % (K / 8);
        *(uint4*)(Bs + n * BSTR + kc * 8) =
            *(const uint4*)(Bt + (size_t)(n0 + n) * K + kc * 8);
    }
    f32x4 acc[2][4] = {};
    const int q = lane >> 4, c = lane & 15;
    const int r_st = tid >> 1, hh = tid & 1;
    for (int k0 = 0; k0 < K; k0 += 32) {
        int gr = row0 + r_st;
        uint4 av0 = make_uint4(0, 0, 0, 0), av1 = make_uint4(0, 0, 0, 0);
        if (gr < M) {
            if (CASTA) {
                const float* A = (const float*)Av;
                const float* ap = A + (size_t)gr * K + k0 + hh * 16;
                float4 f0 = *(const float4*)(ap);
                float4 f1 = *(const float4*)(ap + 4);
                float4 f2 = *(const float4*)(ap + 8);
                float4 f3 = *(const float4*)(ap + 12);
                ushort4 u0, u1, u2, u3;
                u0.x = f2bf(f0.x); u0.y = f2bf(f0.y); u0.z = f2bf(f0.z); u0.w = f2bf(f0.w);
                u1.x = f2bf(f1.x); u1.y = f2bf(f1.y); u1.z = f2bf(f1.z); u1.w = f2bf(f1.w);
                u2.x = f2bf(f2.x); u2.y = f2bf(f2.y); u2.z = f2bf(f2.z); u2.w = f2bf(f2.w);
                u3.x = f2bf(f3.x); u3.y = f2bf(f3.y); u3.z = f2bf(f3.z); u3.w = f2bf(f3.w);
                av0 = make_uint4(((unsigned)u0.y << 16) | u0.x, ((unsigned)u0.w << 16) | u0.z,
                                 ((unsigned)u1.y << 16) | u1.x, ((unsigned)u1.w << 16) | u1.z);
                av1 = make_uint4(((unsigned)u2.y << 16) | u2.x, ((unsigned)u2.w << 16) | u2.z,
                                 ((unsigned)u3.y << 16) | u3.x, ((unsigned)u3.w << 16) | u3.z);
            } else {
                const unsigned short* A = (const unsigned short*)Av;
                const unsigned short* ap = A + (size_t)gr * K + k0 + hh * 16;
                av0 = *(const uint4*)(ap);
                av1 = *(const uint4*)(ap + 8);
            }
        }
        __syncthreads();
        *(uint4*)(As + r_st * ASTR + hh * 16) = av0;
        *(uint4*)(As + r_st * ASTR + hh * 16 + 8) = av1;
        __syncthreads();
        bf16x8 af[2], bfr[4];
        af[0] = *(const bf16x8*)(As + (w * 32 + c) * ASTR + q * 8);
        af[1] = *(const bf16x8*)(As + (w * 32 + 16 + c) * ASTR + q * 8);
#pragma unroll
        for (int nt = 0; nt < 4; ++nt)
            bfr[nt] = *(const bf16x8*)(Bs + (nt * 16 + c) * BSTR + k0 + q * 8);
#pragma unroll
        for (int mt = 0; mt < 2; ++mt)
#pragma unroll
            for (int nt = 0; nt < 4; ++nt)
                acc[mt][nt] = __builtin_amdgcn_mfma_f32_16x16x32_bf16(
                    af[mt], bfr[nt], acc[mt][nt], 0, 0, 0);
    }
    float alv[4], arv[4];
#pragma unroll
    for (int nt = 0; nt < 4; ++nt) {
        alv[nt] = al[n0 + nt * 16 + c];
        arv[nt] = ar[n0 + nt * 16 + c];
    }
    const int head = n0 >> 6;
#pragma unroll
    for (int mt = 0; mt < 2; ++mt) {
#pragma unroll
        for (int r = 0; r < 4; ++r) {
            int grow = row0 + w * 32 + mt * 16 + q * 4 + r;
            bool ok = grow < M;
            float elp = 0.f, erp = 0.f;
#pragma unroll
            for (int nt = 0; nt < 4; ++nt) {
                float v = acc[mt][nt][r];
                elp += v * alv[nt];
                erp += v * arv[nt];
                if (ok) C[(size_t)grow * NC + n0 + nt * 16 + c] = f2bf(v);
            }
#pragma unroll
            for (int o = 8; o > 0; o >>= 1) {
                elp += __shfl_down(elp, o, 16);
                erp += __shfl_down(erp, o, 16);
            }
            if (c == 0 && ok) {
                el[(size_t)grow * H + head] = elp;
                er[(size_t)grow * H + head] = erp;
            }
        }
    }
}

// ================= CSR build =================
__global__ __launch_bounds__(256) void degree_kernel(
    const int* __restrict__ dst, int* __restrict__ deg, int E) {
    int e = blockIdx.x * 256 + threadIdx.x;
    if (e < E) atomicAdd(&deg[dst[e]], 1);
}

__global__ __launch_bounds__(256) void scan_block_kernel(
    const int* __restrict__ deg, int* __restrict__ off,
    int* __restrict__ bsum, int N) {
    __shared__ int s[256];
    int i = blockIdx.x * 256 + threadIdx.x;
    int v = (i < N) ? deg[i] : 0;
    s[threadIdx.x] = v;
    __syncthreads();
    for (int d = 1; d < 256; d <<= 1) {
        int t = (threadIdx.x >= d) ? s[threadIdx.x - d] : 0;
        __syncthreads();
        s[threadIdx.x] += t;
        __syncthreads();
    }
    if (i < N) off[i] = s[threadIdx.x] - v;
    if (threadIdx.x == 255) bsum[blockIdx.x] = s[255];
}

__global__ __launch_bounds__(512) void scan_partials_kernel(int* __restrict__ bsum, int nb) {
    __shared__ int s[512];
    int v = (threadIdx.x < nb) ? bsum[threadIdx.x] : 0;
    s[threadIdx.x] = v;
    __syncthreads();
    for (int d = 1; d < 512; d <<= 1) {
        int t = (threadIdx.x >= d) ? s[threadIdx.x - d] : 0;
        __syncthreads();
        s[threadIdx.x] += t;
        __syncthreads();
    }
    if (threadIdx.x < nb) bsum[threadIdx.x] = s[threadIdx.x] - v;
}

__global__ __launch_bounds__(256) void add_offsets_kernel(
    int* __restrict__ off, const int* __restrict__ bsum, int N, int E) {
    int i = blockIdx.x * 256 + threadIdx.x;
    if (i < N) off[i] += bsum[blockIdx.x];
    if (i == 0) off[N] = E;
}

__global__ __launch_bounds__(256) void fill_csr_kernel(
    const int* __restrict__ src, const int* __restrict__ dst,
    int* __restrict__ cur, int* __restrict__ csr_src, int E) {
    int e = blockIdx.x * 256 + threadIdx.x;
    if (e >= E) return;
    int d = dst[e];
    int pos = atomicAdd(&cur[d], 1);
    csr_src[pos] = src[e];
}

// ===== Layer 0 fused gather: w=exp(leaky(el+er)) inline (no max-sub; scores
// bounded ±~15 << 88, alpha/denom shift-invariant) + bias + leaky + noise =====
__global__ __launch_bounds__(256) void agg0_kernel(
    const int* __restrict__ off, const int* __restrict__ csr_src,
    const unsigned short* __restrict__ h,   // [N,256] bf16
    const float* __restrict__ el,           // [N,4] (L2-resident, broadcast)
    const float* __restrict__ er,
    const float* __restrict__ b0, const float* __restrict__ noise,
    unsigned short* __restrict__ out, int N) {
    int gt = blockIdx.x * 256 + threadIdx.x;
    int n = gt >> 6;
    int lane = gt & 63;
    if (n >= N) return;
    int hd = lane >> 4;
    float ern = er[(size_t)n * 4 + hd];
    int beg = off[n], end = off[n + 1];
    float ax = 0.f, ay = 0.f, az = 0.f, aw = 0.f, l = 0.f;
    int p = beg;
    for (; p + 2 <= end; p += 2) {
        int s0 = csr_src[p], s1 = csr_src[p + 1];
        float e0 = el[(size_t)s0 * 4 + hd] + ern;
        float e1 = el[(size_t)s1 * 4 + hd] + ern;
        e0 = e0 > 0.f ? e0 : 0.2f * e0;
        e1 = e1 > 0.f ? e1 : 0.2f * e1;
        float w0 = __expf(e0), w1 = __expf(e1);
        ushort4 u0 = *(const ushort4*)(h + (size_t)s0 * HD0 + lane * 4);
        ushort4 u1 = *(const ushort4*)(h + (size_t)s1 * HD0 + lane * 4);
        ax += w0 * bf2f(u0.x) + w1 * bf2f(u1.x);
        ay += w0 * bf2f(u0.y) + w1 * bf2f(u1.y);
        az += w0 * bf2f(u0.z) + w1 * bf2f(u1.z);
        aw += w0 * bf2f(u0.w) + w1 * bf2f(u1.w);
        l += w0 + w1;
    }
    if (p < end) {
        int s0 = csr_src[p];
        float e0 = el[(size_t)s0 * 4 + hd] + ern;
        e0 = e0 > 0.f ? e0 : 0.2f * e0;
        float w0 = __expf(e0);
        ushort4 u0 = *(const ushort4*)(h + (size_t)s0 * HD0 + lane * 4);
        ax += w0 * bf2f(u0.x);
        ay += w0 * bf2f(u0.y);
        az += w0 * bf2f(u0.z);
        aw += w0 * bf2f(u0.w);
        l += w0;
    }
    float rd = 1.f / l;  // self-loop guarantees l > 0
    const float4 bv = *(const float4*)(b0 + lane * 4);
    const float4 nv = *(const float4*)(noise + (size_t)n * HD0 + lane * 4);
    float ox = ax * rd + bv.x; ox = ox > 0.f ? ox : 0.01f * ox; ox += NOISE_SCALE * nv.x;
    float oy = ay * rd + bv.y; oy = oy > 0.f ? oy : 0.01f * oy; oy += NOISE_SCALE * nv.y;
    float oz = az * rd + bv.z; oz = oz > 0.f ? oz : 0.01f * oz; oz += NOISE_SCALE * nv.z;
    float ow = aw * rd + bv.w; ow = ow > 0.f ? ow : 0.01f * ow; ow += NOISE_SCALE * nv.w;
    ushort4 o;
    o.x = f2bf(ox); o.y = f2bf(oy); o.z = f2bf(oz); o.w = f2bf(ow);
    *(ushort4*)(out + (size_t)n * HD0 + lane * 4) = o;
}

// ===== Layer 1 fused gather: inline exp weights + bias -> fp32 =====
__global__ __launch_bounds__(256) void agg1_kernel(
    const int* __restrict__ off, const int* __restrict__ csr_src,
    const unsigned short* __restrict__ h,   // [N,64] bf16
    const float* __restrict__ el,           // [N]
    const float* __restrict__ er,
    const float* __restrict__ b1, float* __restrict__ out, int N) {
    int gt = blockIdx.x * 256 + threadIdx.x;
    int n = gt >> 6;
    int lane = gt & 63;
    if (n >= N) return;
    float ern = er[n];
    int beg = off[n], end = off[n + 1];
    float acc = 0.f, l = 0.f;
    int p = beg;
    for (; p + 2 <= end; p += 2) {
        int s0 = csr_src[p], s1 = csr_src[p + 1];
        float e0 = el[s0] + ern, e1 = el[s1] + ern;
        e0 = e0 > 0.f ? e0 : 0.2f * e0;
        e1 = e1 > 0.f ? e1 : 0.2f * e1;
        float w0 = __expf(e0), w1 = __expf(e1);
        float v0 = bf2f(h[(size_t)s0 * 64 + lane]);
        float v1 = bf2f(h[(size_t)s1 * 64 + lane]);
        acc += w0 * v0 + w1 * v1;
        l += w0 + w1;
    }
    if (p < end) {
        int s0 = csr_src[p];
        float e0 = el[s0] + ern;
        e0 = e0 > 0.f ? e0 : 0.2f * e0;
        float w0 = __expf(e0);
        acc += w0 * bf2f(h[(size_t)s0 * 64 + lane]);
        l += w0;
    }
    out[(size_t)n * 64 + lane] = acc / l + b1[lane];
}

extern "C" void kernel_launch(void* const* d_in, const int* in_sizes, int n_in,
                              void* d_out, int out_size, void* d_ws, size_t ws_size,
                              hipStream_t stream) {
    const float* x     = (const float*)d_in[0];
    const int*   src   = (const int*)d_in[1];
    const int*   dst   = (const int*)d_in[2];
    const float* W0    = (const float*)d_in[3];
    const float* al0   = (const float*)d_in[4];
    const float* ar0   = (const float*)d_in[5];
    const float* b0    = (const float*)d_in[6];
    const float* W1    = (const float*)d_in[7];
    const float* al1   = (const float*)d_in[8];
    const float* ar1   = (const float*)d_in[9];
    const float* b1    = (const float*)d_in[10];
    const float* noise = (const float*)d_in[11];

    const int N = in_sizes[0] / IN_F;   // 100000
    const int E = in_sizes[1];          // 900000
    const int NB = (N + 255) / 256;

    // Workspace layout
    char* p = (char*)d_ws;
    unsigned short* h0     = (unsigned short*)p; p += (size_t)N * HD0 * 2;
    unsigned short* agg0b  = (unsigned short*)p; p += (size_t)N * HD0 * 2;
    unsigned short* h1     = (unsigned short*)p; p += (size_t)N * OUT_F * 2;
    unsigned short* W0t    = (unsigned short*)p; p += (size_t)IN_F * HD0 * 2;
    unsigned short* W1t    = (unsigned short*)p; p += (size_t)HD0 * OUT_F * 2;
    float* el     = (float*)p; p += (size_t)N * HEADS * 4;
    float* er     = (float*)p; p += (size_t)N * HEADS * 4;
    int* deg    = (int*)p; p += (size_t)N * 4;
    int* cur    = (int*)p; p += (size_t)N * 4;
    int* off    = (int*)p; p += ((size_t)N + 4) * 4;
    int* bsum   = (int*)p; p += 512 * 4;
    int* csr_src= (int*)p; p += (size_t)E * 4;

    // ---------- weight transposes ----------
    tcast_kernel<<<(IN_F * HD0 + 255) / 256, 256, 0, stream>>>(W0, W0t, IN_F, HD0);
    tcast_kernel<<<(HD0 * OUT_F + 255) / 256, 256, 0, stream>>>(W1, W1t, HD0, OUT_F);

    // ---------- CSR build ----------
    hipMemsetAsync(deg, 0, (size_t)N * sizeof(int), stream);
    degree_kernel<<<(E + 255) / 256, 256, 0, stream>>>(dst, deg, E);
    scan_block_kernel<<<NB, 256, 0, stream>>>(deg, off, bsum, N);
    scan_partials_kernel<<<1, 512, 0, stream>>>(bsum, NB);
    add_offsets_kernel<<<NB, 256, 0, stream>>>(off, bsum, N, E);
    hipMemcpyAsync(cur, off, (size_t)N * sizeof(int), hipMemcpyDeviceToDevice, stream);
    fill_csr_kernel<<<(E + 255) / 256, 256, 0, stream>>>(src, dst, cur, csr_src, E);

    const int MB = (N + 127) / 128;   // 782

    // ---------- Layer 0 ----------
    {
        dim3 grid(HD0 / 64, MB);
        gemm_fused_kernel<IN_F, true, HEADS><<<grid, 256, 0, stream>>>(
            x, W0t, h0, al0, ar0, el, er, N, HD0);
    }
    agg0_kernel<<<(N * 64 + 255) / 256, 256, 0, stream>>>(
        off, csr_src, h0, el, er, b0, noise, agg0b, N);

    // ---------- Layer 1 ----------
    {
        dim3 grid(OUT_F / 64, MB);
        gemm_fused_kernel<HD0, false, 1><<<grid, 256, 0, stream>>>(
            agg0b, W1t, h1, al1, ar1, el, er, N, OUT_F);
    }
    agg1_kernel<<<(N * 64 + 255) / 256, 256, 0, stream>>>(
        off, csr_src, h1, el, er, b1, (float*)d_out, N);
}

// Round 7
// 480.126 us; speedup vs baseline: 3.5445x; 1.0466x over previous
//
#include <hip/hip_runtime.h>
#include <hip/hip_bf16.h>
#include <math.h>

#define IN_F 128
#define HID 64
#define HEADS 4
#define HD0 (HEADS * HID)   // 256
#define OUT_F 64
#define NOISE_SCALE 2.5372725354060904f

typedef __bf16 bf16x8 __attribute__((ext_vector_type(8)));
typedef float f32x4 __attribute__((ext_vector_type(4)));

__device__ __forceinline__ float bf2f(unsigned short u) {
    return __uint_as_float(((unsigned)u) << 16);
}
__device__ __forceinline__ unsigned short f2bf(float f) {
    unsigned u = __float_as_uint(f);
    u = u + 0x7fffu + ((u >> 16) & 1u);  // round-nearest-even
    return (unsigned short)(u >> 16);
}

// ---------- cast x fp32 -> bf16, 8 elems/thread ----------
__global__ __launch_bounds__(256) void cast_bf16_kernel(
    const float* __restrict__ in, unsigned short* __restrict__ out, size_t n8) {
    size_t i = (size_t)blockIdx.x * 256 + threadIdx.x;
    if (i >= n8) return;
    const float4 a = ((const float4*)in)[i * 2];
    const float4 b = ((const float4*)in)[i * 2 + 1];
    ushort4 o0, o1;
    o0.x = f2bf(a.x); o0.y = f2bf(a.y); o0.z = f2bf(a.z); o0.w = f2bf(a.w);
    o1.x = f2bf(b.x); o1.y = f2bf(b.y); o1.z = f2bf(b.z); o1.w = f2bf(b.w);
    ((ushort4*)out)[i * 2] = o0;
    ((ushort4*)out)[i * 2 + 1] = o1;
}

// ---------- transpose+cast W [K][NC] -> Wt [NC][K] bf16 ----------
__global__ __launch_bounds__(256) void tcast_kernel(
    const float* __restrict__ W, unsigned short* __restrict__ Wt, int K, int NC) {
    int i = blockIdx.x * 256 + threadIdx.x;
    if (i >= K * NC) return;
    int n = i / K, k = i % K;
    Wt[n * K + k] = f2bf(W[(size_t)k * NC + n]);
}

// ---------- MFMA GEMM + fused el/er epilogue (A bf16) ----------
template <int K, int H>
__global__ __launch_bounds__(256) void gemm_fused_kernel(
    const unsigned short* __restrict__ A, const unsigned short* __restrict__ Bt,
    unsigned short* __restrict__ C, const float* __restrict__ al,
    const float* __restrict__ ar, float* __restrict__ el,
    float* __restrict__ er, int M, int NC) {
    constexpr int BSTR = K + 8;
    constexpr int ASTR = 40;
    __shared__ __align__(16) unsigned short Bs[64 * BSTR];
    __shared__ __align__(16) unsigned short As[128 * ASTR];
    const int tid = threadIdx.x;
    const int lane = tid & 63, w = tid >> 6;
    const int row0 = blockIdx.y * 128;
    const int n0 = blockIdx.x * 64;
    for (int i = tid; i < 64 * (K / 8); i += 256) {
        int n = i / (K / 8), kc = i % (K / 8);
        *(uint4*)(Bs + n * BSTR + kc * 8) =
            *(const uint4*)(Bt + (size_t)(n0 + n) * K + kc * 8);
    }
    f32x4 acc[2][4] = {};
    const int q = lane >> 4, c = lane & 15;
    const int r_st = tid >> 1, hh = tid & 1;
    for (int k0 = 0; k0 < K; k0 += 32) {
        int gr = row0 + r_st;
        uint4 av0 = make_uint4(0, 0, 0, 0), av1 = make_uint4(0, 0, 0, 0);
        if (gr < M) {
            const unsigned short* ap = A + (size_t)gr * K + k0 + hh * 16;
            av0 = *(const uint4*)(ap);
            av1 = *(const uint4*)(ap + 8);
        }
        __syncthreads();
        *(uint4*)(As + r_st * ASTR + hh * 16) = av0;
        *(uint4*)(As + r_st * ASTR + hh * 16 + 8) = av1;
        __syncthreads();
        bf16x8 af[2], bfr[4];
        af[0] = *(const bf16x8*)(As + (w * 32 + c) * ASTR + q * 8);
        af[1] = *(const bf16x8*)(As + (w * 32 + 16 + c) * ASTR + q * 8);
#pragma unroll
        for (int nt = 0; nt < 4; ++nt)
            bfr[nt] = *(const bf16x8*)(Bs + (nt * 16 + c) * BSTR + k0 + q * 8);
#pragma unroll
        for (int mt = 0; mt < 2; ++mt)
#pragma unroll
            for (int nt = 0; nt < 4; ++nt)
                acc[mt][nt] = __builtin_amdgcn_mfma_f32_16x16x32_bf16(
                    af[mt], bfr[nt], acc[mt][nt], 0, 0, 0);
    }
    float alv[4], arv[4];
#pragma unroll
    for (int nt = 0; nt < 4; ++nt) {
        alv[nt] = al[n0 + nt * 16 + c];
        arv[nt] = ar[n0 + nt * 16 + c];
    }
    const int head = n0 >> 6;
#pragma unroll
    for (int mt = 0; mt < 2; ++mt) {
#pragma unroll
        for (int r = 0; r < 4; ++r) {
            int grow = row0 + w * 32 + mt * 16 + q * 4 + r;
            bool ok = grow < M;
            float elp = 0.f, erp = 0.f;
#pragma unroll
            for (int nt = 0; nt < 4; ++nt) {
                float v = acc[mt][nt][r];
                elp += v * alv[nt];
                erp += v * arv[nt];
                if (ok) C[(size_t)grow * NC + n0 + nt * 16 + c] = f2bf(v);
            }
#pragma unroll
            for (int o = 8; o > 0; o >>= 1) {
                elp += __shfl_down(elp, o, 16);
                erp += __shfl_down(erp, o, 16);
            }
            if (c == 0 && ok) {
                el[(size_t)grow * H + head] = elp;
                er[(size_t)grow * H + head] = erp;
            }
        }
    }
}

// ================= CSR build =================
__global__ __launch_bounds__(256) void degree_kernel(
    const int* __restrict__ dst, int* __restrict__ deg, int E) {
    int e = blockIdx.x * 256 + threadIdx.x;
    if (e < E) atomicAdd(&deg[dst[e]], 1);
}

__global__ __launch_bounds__(256) void scan_block_kernel(
    const int* __restrict__ deg, int* __restrict__ off,
    int* __restrict__ bsum, int N) {
    __shared__ int s[256];
    int i = blockIdx.x * 256 + threadIdx.x;
    int v = (i < N) ? deg[i] : 0;
    s[threadIdx.x] = v;
    __syncthreads();
    for (int d = 1; d < 256; d <<= 1) {
        int t = (threadIdx.x >= d) ? s[threadIdx.x - d] : 0;
        __syncthreads();
        s[threadIdx.x] += t;
        __syncthreads();
    }
    if (i < N) off[i] = s[threadIdx.x] - v;
    if (threadIdx.x == 255) bsum[blockIdx.x] = s[255];
}

__global__ __launch_bounds__(512) void scan_partials_kernel(int* __restrict__ bsum, int nb) {
    __shared__ int s[512];
    int v = (threadIdx.x < nb) ? bsum[threadIdx.x] : 0;
    s[threadIdx.x] = v;
    __syncthreads();
    for (int d = 1; d < 512; d <<= 1) {
        int t = (threadIdx.x >= d) ? s[threadIdx.x - d] : 0;
        __syncthreads();
        s[threadIdx.x] += t;
        __syncthreads();
    }
    if (threadIdx.x < nb) bsum[threadIdx.x] = s[threadIdx.x] - v;
}

// also writes cur[] so fill_csr needs no memcpy
__global__ __launch_bounds__(256) void add_offsets_kernel(
    int* __restrict__ off, int* __restrict__ cur,
    const int* __restrict__ bsum, int N, int E) {
    int i = blockIdx.x * 256 + threadIdx.x;
    if (i < N) {
        int v = off[i] + bsum[blockIdx.x];
        off[i] = v;
        cur[i] = v;
    }
    if (i == 0) off[N] = E;
}

__global__ __launch_bounds__(256) void fill_csr_kernel(
    const int* __restrict__ src, const int* __restrict__ dst,
    int* __restrict__ cur, int* __restrict__ csr_src, int E) {
    int e = blockIdx.x * 256 + threadIdx.x;
    if (e >= E) return;
    int d = dst[e];
    int pos = atomicAdd(&cur[d], 1);
    csr_src[pos] = src[e];
}

// ===== Layer 0 fused gather (unroll 4 for MLP) =====
__global__ __launch_bounds__(256) void agg0_kernel(
    const int* __restrict__ off, const int* __restrict__ csr_src,
    const unsigned short* __restrict__ h,   // [N,256] bf16
    const float* __restrict__ el,           // [N,4]
    const float* __restrict__ er,
    const float* __restrict__ b0, const float* __restrict__ noise,
    unsigned short* __restrict__ out, int N) {
    int gt = blockIdx.x * 256 + threadIdx.x;
    int n = gt >> 6;
    int lane = gt & 63;
    if (n >= N) return;
    int hd = lane >> 4;
    float ern = er[(size_t)n * 4 + hd];
    int beg = off[n], end = off[n + 1];
    float ax = 0.f, ay = 0.f, az = 0.f, aw = 0.f, l = 0.f;
    int p = beg;
    for (; p + 4 <= end; p += 4) {
        int s0 = csr_src[p], s1 = csr_src[p + 1];
        int s2 = csr_src[p + 2], s3 = csr_src[p + 3];
        float e0 = el[(size_t)s0 * 4 + hd];
        float e1 = el[(size_t)s1 * 4 + hd];
        float e2 = el[(size_t)s2 * 4 + hd];
        float e3 = el[(size_t)s3 * 4 + hd];
        ushort4 u0 = *(const ushort4*)(h + (size_t)s0 * HD0 + lane * 4);
        ushort4 u1 = *(const ushort4*)(h + (size_t)s1 * HD0 + lane * 4);
        ushort4 u2 = *(const ushort4*)(h + (size_t)s2 * HD0 + lane * 4);
        ushort4 u3 = *(const ushort4*)(h + (size_t)s3 * HD0 + lane * 4);
        e0 += ern; e1 += ern; e2 += ern; e3 += ern;
        e0 = e0 > 0.f ? e0 : 0.2f * e0;
        e1 = e1 > 0.f ? e1 : 0.2f * e1;
        e2 = e2 > 0.f ? e2 : 0.2f * e2;
        e3 = e3 > 0.f ? e3 : 0.2f * e3;
        float w0 = __expf(e0), w1 = __expf(e1), w2 = __expf(e2), w3 = __expf(e3);
        ax += w0 * bf2f(u0.x) + w1 * bf2f(u1.x) + w2 * bf2f(u2.x) + w3 * bf2f(u3.x);
        ay += w0 * bf2f(u0.y) + w1 * bf2f(u1.y) + w2 * bf2f(u2.y) + w3 * bf2f(u3.y);
        az += w0 * bf2f(u0.z) + w1 * bf2f(u1.z) + w2 * bf2f(u2.z) + w3 * bf2f(u3.z);
        aw += w0 * bf2f(u0.w) + w1 * bf2f(u1.w) + w2 * bf2f(u2.w) + w3 * bf2f(u3.w);
        l += (w0 + w1) + (w2 + w3);
    }
    for (; p < end; ++p) {
        int s0 = csr_src[p];
        float e0 = el[(size_t)s0 * 4 + hd] + ern;
        e0 = e0 > 0.f ? e0 : 0.2f * e0;
        float w0 = __expf(e0);
        ushort4 u0 = *(const ushort4*)(h + (size_t)s0 * HD0 + lane * 4);
        ax += w0 * bf2f(u0.x);
        ay += w0 * bf2f(u0.y);
        az += w0 * bf2f(u0.z);
        aw += w0 * bf2f(u0.w);
        l += w0;
    }
    float rd = 1.f / l;
    const float4 bv = *(const float4*)(b0 + lane * 4);
    const float4 nv = *(const float4*)(noise + (size_t)n * HD0 + lane * 4);
    float ox = ax * rd + bv.x; ox = ox > 0.f ? ox : 0.01f * ox; ox += NOISE_SCALE * nv.x;
    float oy = ay * rd + bv.y; oy = oy > 0.f ? oy : 0.01f * oy; oy += NOISE_SCALE * nv.y;
    float oz = az * rd + bv.z; oz = oz > 0.f ? oz : 0.01f * oz; oz += NOISE_SCALE * nv.z;
    float ow = aw * rd + bv.w; ow = ow > 0.f ? ow : 0.01f * ow; ow += NOISE_SCALE * nv.w;
    ushort4 o;
    o.x = f2bf(ox); o.y = f2bf(oy); o.z = f2bf(oz); o.w = f2bf(ow);
    *(ushort4*)(out + (size_t)n * HD0 + lane * 4) = o;
}

// ===== Layer 1 fused gather (unroll 4) + bias -> fp32 =====
__global__ __launch_bounds__(256) void agg1_kernel(
    const int* __restrict__ off, const int* __restrict__ csr_src,
    const unsigned short* __restrict__ h,   // [N,64] bf16
    const float* __restrict__ el,           // [N]
    const float* __restrict__ er,
    const float* __restrict__ b1, float* __restrict__ out, int N) {
    int gt = blockIdx.x * 256 + threadIdx.x;
    int n = gt >> 6;
    int lane = gt & 63;
    if (n >= N) return;
    float ern = er[n];
    int beg = off[n], end = off[n + 1];
    float acc = 0.f, l = 0.f;
    int p = beg;
    for (; p + 4 <= end; p += 4) {
        int s0 = csr_src[p], s1 = csr_src[p + 1];
        int s2 = csr_src[p + 2], s3 = csr_src[p + 3];
        float e0 = el[s0], e1 = el[s1], e2 = el[s2], e3 = el[s3];
        float v0 = bf2f(h[(size_t)s0 * 64 + lane]);
        float v1 = bf2f(h[(size_t)s1 * 64 + lane]);
        float v2 = bf2f(h[(size_t)s2 * 64 + lane]);
        float v3 = bf2f(h[(size_t)s3 * 64 + lane]);
        e0 += ern; e1 += ern; e2 += ern; e3 += ern;
        e0 = e0 > 0.f ? e0 : 0.2f * e0;
        e1 = e1 > 0.f ? e1 : 0.2f * e1;
        e2 = e2 > 0.f ? e2 : 0.2f * e2;
        e3 = e3 > 0.f ? e3 : 0.2f * e3;
        float w0 = __expf(e0), w1 = __expf(e1), w2 = __expf(e2), w3 = __expf(e3);
        acc += w0 * v0 + w1 * v1 + w2 * v2 + w3 * v3;
        l += (w0 + w1) + (w2 + w3);
    }
    for (; p < end; ++p) {
        int s0 = csr_src[p];
        float e0 = el[s0] + ern;
        e0 = e0 > 0.f ? e0 : 0.2f * e0;
        float w0 = __expf(e0);
        acc += w0 * bf2f(h[(size_t)s0 * 64 + lane]);
        l += w0;
    }
    out[(size_t)n * 64 + lane] = acc / l + b1[lane];
}

extern "C" void kernel_launch(void* const* d_in, const int* in_sizes, int n_in,
                              void* d_out, int out_size, void* d_ws, size_t ws_size,
                              hipStream_t stream) {
    const float* x     = (const float*)d_in[0];
    const int*   src   = (const int*)d_in[1];
    const int*   dst   = (const int*)d_in[2];
    const float* W0    = (const float*)d_in[3];
    const float* al0   = (const float*)d_in[4];
    const float* ar0   = (const float*)d_in[5];
    const float* b0    = (const float*)d_in[6];
    const float* W1    = (const float*)d_in[7];
    const float* al1   = (const float*)d_in[8];
    const float* ar1   = (const float*)d_in[9];
    const float* b1    = (const float*)d_in[10];
    const float* noise = (const float*)d_in[11];

    const int N = in_sizes[0] / IN_F;   // 100000
    const int E = in_sizes[1];          // 900000
    const int NB = (N + 255) / 256;

    // Workspace layout
    char* p = (char*)d_ws;
    unsigned short* x_bf   = (unsigned short*)p; p += (size_t)N * IN_F * 2;
    unsigned short* h0     = (unsigned short*)p; p += (size_t)N * HD0 * 2;
    unsigned short* agg0b  = (unsigned short*)p; p += (size_t)N * HD0 * 2;
    unsigned short* h1     = (unsigned short*)p; p += (size_t)N * OUT_F * 2;
    unsigned short* W0t    = (unsigned short*)p; p += (size_t)IN_F * HD0 * 2;
    unsigned short* W1t    = (unsigned short*)p; p += (size_t)HD0 * OUT_F * 2;
    float* el     = (float*)p; p += (size_t)N * HEADS * 4;
    float* er     = (float*)p; p += (size_t)N * HEADS * 4;
    int* deg    = (int*)p; p += (size_t)N * 4;
    int* cur    = (int*)p; p += (size_t)N * 4;
    int* off    = (int*)p; p += ((size_t)N + 4) * 4;
    int* bsum   = (int*)p; p += 512 * 4;
    int* csr_src= (int*)p; p += (size_t)E * 4;

    // ---------- casts ----------
    {
        size_t n8 = (size_t)N * IN_F / 8;
        cast_bf16_kernel<<<(unsigned)((n8 + 255) / 256), 256, 0, stream>>>(x, x_bf, n8);
    }
    tcast_kernel<<<(IN_F * HD0 + 255) / 256, 256, 0, stream>>>(W0, W0t, IN_F, HD0);
    tcast_kernel<<<(HD0 * OUT_F + 255) / 256, 256, 0, stream>>>(W1, W1t, HD0, OUT_F);

    // ---------- CSR build ----------
    hipMemsetAsync(deg, 0, (size_t)N * sizeof(int), stream);
    degree_kernel<<<(E + 255) / 256, 256, 0, stream>>>(dst, deg, E);
    scan_block_kernel<<<NB, 256, 0, stream>>>(deg, off, bsum, N);
    scan_partials_kernel<<<1, 512, 0, stream>>>(bsum, NB);
    add_offsets_kernel<<<NB, 256, 0, stream>>>(off, cur, bsum, N, E);
    fill_csr_kernel<<<(E + 255) / 256, 256, 0, stream>>>(src, dst, cur, csr_src, E);

    const int MB = (N + 127) / 128;   // 782

    // ---------- Layer 0 ----------
    {
        dim3 grid(HD0 / 64, MB);
        gemm_fused_kernel<IN_F, HEADS><<<grid, 256, 0, stream>>>(
            x_bf, W0t, h0, al0, ar0, el, er, N, HD0);
    }
    agg0_kernel<<<(N * 64 + 255) / 256, 256, 0, stream>>>(
        off, csr_src, h0, el, er, b0, noise, agg0b, N);

    // ---------- Layer 1 ----------
    {
        dim3 grid(OUT_F / 64, MB);
        gemm_fused_kernel<HD0, 1><<<grid, 256, 0, stream>>>(
            agg0b, W1t, h1, al1, ar1, el, er, N, OUT_F);
    }
    agg1_kernel<<<(N * 64 + 255) / 256, 256, 0, stream>>>(
        off, csr_src, h1, el, er, b1, (float*)d_out, N);
}